// Round 5
// baseline (1403.285 us; speedup 1.0000x reference)
//
#include <hip/hip_runtime.h>
#include <hip/hip_fp16.h>

// ---------------- problem constants ----------------
constexpr int N_ROWS = 4096;
constexpr int VOCAB  = 50000;
constexpr int DIM    = 300;
constexpr int DP     = 320;           // DIM padded to 10 * 32
constexpr long long VP = 50176;       // VOCAB padded to 8 * 6272
constexpr int VSLICE = 8;
constexpr int SLICE  = 6272;          // 196 * 32
constexpr int BK     = 32;
constexpr int NTILE  = 196;
constexpr int RB     = 32;            // 4096 / 128 q-rows per block

typedef __attribute__((ext_vector_type(8))) _Float16 half8;
typedef __attribute__((ext_vector_type(4))) float floatx4;
typedef __attribute__((ext_vector_type(4))) unsigned int uintx4;

// ---------------- workspace layout (bytes) ----------------
constexpr size_t OFF_PROJ_HI = 0;                          // fp16 [4096][320]
constexpr size_t OFF_PROJ_LO = 2621440;                    // fp16 [4096][320]
constexpr size_t OFF_SDEF    = 5242880;                    // f32  [4096]
constexpr size_t OFF_VH      = 5259264;                    // fp16 [50176][320]
constexpr size_t OFF_VT      = 37371904;                   // fp16 [320][50176]
constexpr size_t OFF_OP      = 69484544;                   // f32  [8][4096][320]
constexpr size_t OFF_MP      = 111427584;                  // f32  [8][4096]
constexpr size_t OFF_LP      = 111558656;                  // f32  [8][4096]

static __device__ __forceinline__ unsigned short f2h(float x) {
    __half h = __float2half(x);
    return __half_as_ushort(h);
}
static __device__ __forceinline__ float h2f(unsigned short u) {
    return __half2float(__ushort_as_half(u));
}

// DPP butterfly reduction over 16-lane rows (verified R2/R4)
static __device__ __forceinline__ float red16_max(float x) {
    x = fmaxf(x, __int_as_float(__builtin_amdgcn_update_dpp(0, __float_as_int(x), 0xB1, 0xF, 0xF, true)));
    x = fmaxf(x, __int_as_float(__builtin_amdgcn_update_dpp(0, __float_as_int(x), 0x4E, 0xF, 0xF, true)));
    x = fmaxf(x, __int_as_float(__builtin_amdgcn_update_dpp(0, __float_as_int(x), 0x141, 0xF, 0xF, true)));
    x = fmaxf(x, __int_as_float(__builtin_amdgcn_update_dpp(0, __float_as_int(x), 0x140, 0xF, 0xF, true)));
    return x;
}
static __device__ __forceinline__ float red16_sum(float x) {
    x += __int_as_float(__builtin_amdgcn_update_dpp(0, __float_as_int(x), 0xB1, 0xF, 0xF, true));
    x += __int_as_float(__builtin_amdgcn_update_dpp(0, __float_as_int(x), 0x4E, 0xF, 0xF, true));
    x += __int_as_float(__builtin_amdgcn_update_dpp(0, __float_as_int(x), 0x141, 0xF, 0xF, true));
    x += __int_as_float(__builtin_amdgcn_update_dpp(0, __float_as_int(x), 0x140, 0xF, 0xF, true));
    return x;
}

static __device__ __forceinline__ void gload16(const void* g, void* l) {
    __builtin_amdgcn_global_load_lds(
        (const __attribute__((address_space(1))) unsigned int*)g,
        (__attribute__((address_space(3))) unsigned int*)l, 16, 0, 0);
}

// ---------------- kernel 1: proj = words @ W (fp16 hi/lo) + s_def (verified) ----------------
__global__ __launch_bounds__(256) void k_proj(const float* __restrict__ words,
                                              const float* __restrict__ W,
                                              const float* __restrict__ de,
                                              unsigned short* __restrict__ proj_hi,
                                              unsigned short* __restrict__ proj_lo,
                                              float* __restrict__ sdef) {
    __shared__ float wrow[16][304];
    __shared__ float red[4][16];
    const int tid = threadIdx.x;
    const int r0  = blockIdx.x * 16;

    for (int i = tid; i < 16 * DIM; i += 256) {
        int r = i / DIM, c = i % DIM;
        wrow[r][c] = words[(size_t)(r0 + r) * DIM + c];
    }
    __syncthreads();

    float sd[16];
    #pragma unroll
    for (int r = 0; r < 16; ++r) sd[r] = 0.f;

    for (int jj = 0; jj < 2; ++jj) {
        int j = tid + jj * 256;
        if (j < DP) {
            float acc[16];
            #pragma unroll
            for (int r = 0; r < 16; ++r) acc[r] = 0.f;
            if (j < DIM) {
                #pragma unroll 4
                for (int k = 0; k < DIM; ++k) {
                    float wk = W[(size_t)k * DIM + j];
                    #pragma unroll
                    for (int r = 0; r < 16; ++r) acc[r] += wrow[r][k] * wk;
                }
                float dj = de[j];
                #pragma unroll
                for (int r = 0; r < 16; ++r) sd[r] += acc[r] * dj;
            }
            #pragma unroll
            for (int r = 0; r < 16; ++r) {
                float x = acc[r];
                unsigned short h = f2h(x);
                proj_hi[(size_t)(r0 + r) * DP + j] = h;
                proj_lo[(size_t)(r0 + r) * DP + j] = f2h(x - h2f(h));
            }
        }
    }

    const int lane = tid & 63, wv = tid >> 6;
    #pragma unroll
    for (int r = 0; r < 16; ++r) {
        float v = sd[r];
        v += __shfl_xor(v, 32); v += __shfl_xor(v, 16);
        v += __shfl_xor(v, 8);  v += __shfl_xor(v, 4);
        v += __shfl_xor(v, 2);  v += __shfl_xor(v, 1);
        if (lane == 0) red[wv][r] = v;
    }
    __syncthreads();
    if (tid < 16) {
        sdef[r0 + tid] = red[0][tid] + red[1][tid] + red[2][tid] + red[3][tid];
    }
}

// ---------------- kernel 2: vocab -> fp16 (padded) + transposed fp16 (verified) ----------------
__global__ __launch_bounds__(256) void k_vocab(const float* __restrict__ vocab,
                                               unsigned short* __restrict__ vh,
                                               unsigned short* __restrict__ vt) {
    __shared__ float tile[64 * 65];
    const int tid = threadIdx.x;
    const int bv = blockIdx.x % 784, bn = blockIdx.x / 784;
    const int v0 = bv * 64, n0 = bn * 64;

    for (int i = tid; i < 64 * 64; i += 256) {
        int r = i >> 6, c = i & 63;
        int v = v0 + r, n = n0 + c;
        float x = (v < VOCAB && n < DIM) ? vocab[(size_t)v * DIM + n] : 0.f;
        tile[r * 65 + c] = x;
    }
    __syncthreads();
    for (int i = tid; i < 64 * 32; i += 256) {
        int r = i >> 5, cp = i & 31;
        float x0 = tile[r * 65 + cp * 2];
        float x1 = tile[r * 65 + cp * 2 + 1];
        unsigned int pack = (unsigned int)f2h(x0) | ((unsigned int)f2h(x1) << 16);
        *(unsigned int*)(vh + (size_t)(v0 + r) * DP + n0 + cp * 2) = pack;
    }
    for (int i = tid; i < 64 * 32; i += 256) {
        int rn = i >> 5, vp = i & 31;
        float y0 = tile[(vp * 2) * 65 + rn];
        float y1 = tile[(vp * 2 + 1) * 65 + rn];
        unsigned int pack = (unsigned int)f2h(y0) | ((unsigned int)f2h(y1) << 16);
        *(unsigned int*)(vt + (size_t)(n0 + rn) * VP + v0 + vp * 2) = pack;
    }
}

// ---------------- kernel 3: fused flash scores+softmax+PV ----------------
// BM=128: 4 waves x 32 q-rows (2 chunks of 16). Grid = 32 rb x 8 slices = 256 blocks,
// exactly 1 block/CU, 1 wave/SIMD, VGPR budget 512 (launch_bounds(256,1)).
// LDS: Vh buf0 [0,20480) | buf1 [20480,40960) | P [40960,49152) 128x64B | scb [49152,49664)
__global__ __launch_bounds__(256, 1) void k_attn(
    const unsigned short* __restrict__ proj_hi,
    const unsigned short* __restrict__ proj_lo,
    const unsigned short* __restrict__ gvh,
    const unsigned short* __restrict__ gvt,
    float* __restrict__ opart,
    float* __restrict__ mpart,
    float* __restrict__ lpart) {
    __shared__ __align__(16) char sm[49664];
    const int tid  = threadIdx.x;
    const int lane = tid & 63;
    const int wv   = tid >> 6;     // 0..3
    const int l15  = lane & 15;
    const int g    = lane >> 4;    // 0..3
    const int bs   = blockIdx.x & 7;   // slice == XCD (round-robin dispatch)
    const int rb   = blockIdx.x >> 3;
    const int qblk = rb * 128;
    const int qw   = qblk + wv * 32;   // this wave's 32 q-rows
    const int vs0  = bs * SLICE;
    const int swz0 = (l15 & 7) << 4;

    // Q fragments (fp16 hi/lo), 2 q-chunks x 10 K-steps
    half8 qh0[10], ql0[10], qh1[10], ql1[10];
    {
        const unsigned short* ph0 = proj_hi + (size_t)(qw + l15) * DP + g * 8;
        const unsigned short* pl0 = proj_lo + (size_t)(qw + l15) * DP + g * 8;
        const unsigned short* ph1 = proj_hi + (size_t)(qw + 16 + l15) * DP + g * 8;
        const unsigned short* pl1 = proj_lo + (size_t)(qw + 16 + l15) * DP + g * 8;
        #pragma unroll
        for (int t = 0; t < 10; ++t) {
            qh0[t] = *(const half8*)(ph0 + t * 32);
            ql0[t] = *(const half8*)(pl0 + t * 32);
            qh1[t] = *(const half8*)(ph1 + t * 32);
            ql1[t] = *(const half8*)(pl1 + t * 32);
        }
    }
    #pragma unroll
    for (int t = 0; t < 10; ++t) {
        asm volatile("" :: "v"(qh0[t]), "v"(ql0[t]), "v"(qh1[t]), "v"(ql1[t]));
    }

    // Vh staging source offsets (pre-swizzled source, linear LDS dst — verified)
    const char* gb = (const char*)gvh;
    unsigned soff[5];
    #pragma unroll
    for (int i = 0; i < 5; ++i) {
        const int j = i * 4 + wv;            // unit 0..19
        const int u = j * 64 + lane;
        const int row = u / 40, s = u - row * 40;
        soff[i] = (unsigned)(vs0 * 640 + row * 640 + ((s ^ (row & 7)) << 4));
    }

    // Vt A-frag global pointers: af[i] = Vt[n=(i*4+wv)*16+l15][v = vs0 + g*8 ..+7]
    const char* vtp[5];
    #pragma unroll
    for (int i = 0; i < 5; ++i) {
        const int n = (i * 4 + wv) * 16 + l15;
        vtp[i] = (const char*)gvt + ((size_t)n * VP + vs0 + g * 8) * 2;
    }

    floatx4 O[5][8];
    #pragma unroll
    for (int a = 0; a < 5; ++a)
        #pragma unroll
        for (int b = 0; b < 8; ++b) O[a][b] = (floatx4){0.f, 0.f, 0.f, 0.f};
    float mx[2][4] = {{-1e30f,-1e30f,-1e30f,-1e30f},{-1e30f,-1e30f,-1e30f,-1e30f}};
    float ls[2][4] = {{0.f,0.f,0.f,0.f},{0.f,0.f,0.f,0.f}};

    char*  Pb  = sm + 40960;
    float* scb = (float*)(sm + 49152);

    // prologue: stage tile 0 into buf0
    #pragma unroll
    for (int i = 0; i < 5; ++i) {
        gload16(gb + soff[i], sm + ((i * 4 + wv) << 10));
        soff[i] += 20480;
    }
    __builtin_amdgcn_sched_barrier(0);
    asm volatile("s_waitcnt vmcnt(0)" ::: "memory");
    __builtin_amdgcn_s_barrier();
    __builtin_amdgcn_sched_barrier(0);

    for (int tau = 0; tau < NTILE; ++tau) {
        const char* buf = sm + (tau & 1) * 20480;
        char*       nxt = sm + ((tau + 1) & 1) * 20480;

        // ---- issue af(t) reg loads FIRST ----
        uintx4 afr[5];
        #pragma unroll
        for (int i = 0; i < 5; ++i) {
            asm volatile("global_load_dwordx4 %0, %1, off"
                         : "=v"(afr[i]) : "v"(vtp[i]) : "memory");
            vtp[i] += 64;
        }
        __builtin_amdgcn_sched_barrier(0);
        // ---- then issue Vh(t+1) staging ----
        #pragma unroll
        for (int i = 0; i < 5; ++i) {
            gload16(gb + soff[i], nxt + ((i * 4 + wv) << 10));
            soff[i] += 20480;
        }
        __builtin_amdgcn_sched_barrier(0);
        // ---- (a): Vh(t) landed; af(t)+Vh(t+1) in flight ----
        asm volatile("s_waitcnt vmcnt(10)" ::: "memory");
        __builtin_amdgcn_s_barrier();
        __builtin_amdgcn_sched_barrier(0);

        // ---- QK^T: S[32 q][32 v], 2-term fp16, 2 q-chunks share each B read ----
        floatx4 s00 = {0.f,0.f,0.f,0.f}, s01 = {0.f,0.f,0.f,0.f};
        floatx4 s10 = {0.f,0.f,0.f,0.f}, s11 = {0.f,0.f,0.f,0.f};
        __builtin_amdgcn_s_setprio(1);
        #pragma unroll
        for (int t = 0; t < 10; ++t) {
            const int koff = (t * 4 + g) << 4;
            half8 bh0 = *(const half8*)(buf + l15 * 640 + (koff ^ swz0));
            half8 bh1 = *(const half8*)(buf + (l15 + 16) * 640 + (koff ^ swz0));
            s00 = __builtin_amdgcn_mfma_f32_16x16x32_f16(qh0[t], bh0, s00, 0, 0, 0);
            s00 = __builtin_amdgcn_mfma_f32_16x16x32_f16(ql0[t], bh0, s00, 0, 0, 0);
            s10 = __builtin_amdgcn_mfma_f32_16x16x32_f16(qh1[t], bh0, s10, 0, 0, 0);
            s10 = __builtin_amdgcn_mfma_f32_16x16x32_f16(ql1[t], bh0, s10, 0, 0, 0);
            s01 = __builtin_amdgcn_mfma_f32_16x16x32_f16(qh0[t], bh1, s01, 0, 0, 0);
            s01 = __builtin_amdgcn_mfma_f32_16x16x32_f16(ql0[t], bh1, s01, 0, 0, 0);
            s11 = __builtin_amdgcn_mfma_f32_16x16x32_f16(qh1[t], bh1, s11, 0, 0, 0);
            s11 = __builtin_amdgcn_mfma_f32_16x16x32_f16(ql1[t], bh1, s11, 0, 0, 0);
        }
        __builtin_amdgcn_s_setprio(0);
        const int vbase = vs0 + tau * BK;
        if (vbase + l15 >= VOCAB) {
            s00[0]=-1e30f; s00[1]=-1e30f; s00[2]=-1e30f; s00[3]=-1e30f;
            s10[0]=-1e30f; s10[1]=-1e30f; s10[2]=-1e30f; s10[3]=-1e30f;
        }
        if (vbase + 16 + l15 >= VOCAB) {
            s01[0]=-1e30f; s01[1]=-1e30f; s01[2]=-1e30f; s01[3]=-1e30f;
            s11[0]=-1e30f; s11[1]=-1e30f; s11[2]=-1e30f; s11[3]=-1e30f;
        }

        // ---- online softmax, defer-max THR=8, both q-chunks ----
        unsigned short pu[2][2][4]; float scv[2][4];
        #pragma unroll
        for (int c = 0; c < 2; ++c) {
            floatx4& a0 = c ? s10 : s00;
            floatx4& a1 = c ? s11 : s01;
            #pragma unroll
            for (int r = 0; r < 4; ++r) {
                float tm = red16_max(fmaxf(a0[r], a1[r]));
                bool grow = tm > mx[c][r] + 8.0f;
                float nm = grow ? tm : mx[c][r];
                float sc = grow ? __expf(mx[c][r] - nm) : 1.0f;
                mx[c][r] = nm;
                float p0 = __expf(a0[r] - nm);
                float p1 = __expf(a1[r] - nm);
                pu[c][0][r] = f2h(p0); pu[c][1][r] = f2h(p1);
                float ps = red16_sum(h2f(pu[c][0][r]) + h2f(pu[c][1][r]));
                ls[c][r] = ls[c][r] * sc + ps;
                scv[c][r] = sc;
            }
        }
        // ---- publish P (rows unit-swizzled by (q>>1)&3) + sc ----
        #pragma unroll
        for (int c = 0; c < 2; ++c) {
            #pragma unroll
            for (int r = 0; r < 4; ++r) {
                const int q = wv * 32 + c * 16 + g * 4 + r;
                const int x = (q >> 1) & 3;
                char* prow = Pb + q * 64 + (l15 & 7) * 2;
                *(unsigned short*)(prow + (((l15 >> 3) ^ x) << 4))       = pu[c][0][r];
                *(unsigned short*)(prow + ((((l15 >> 3) + 2) ^ x) << 4)) = pu[c][1][r];
            }
        }
        if (l15 == 0) {
            #pragma unroll
            for (int c = 0; c < 2; ++c)
                #pragma unroll
                for (int r = 0; r < 4; ++r) scb[wv * 32 + c * 16 + g * 4 + r] = scv[c][r];
        }
        // ---- (b): P visible; prefetch still in flight ----
        __builtin_amdgcn_sched_barrier(0);
        asm volatile("s_waitcnt lgkmcnt(0)" ::: "memory");
        __builtin_amdgcn_s_barrier();
        __builtin_amdgcn_sched_barrier(0);
        // ---- drain af(t) only (Vh(t+1) keeps flying) ----
        asm volatile("s_waitcnt vmcnt(5)" ::: "memory");
        __builtin_amdgcn_sched_barrier(0);

        // ---- PV in O^T form ----
        half8 pf[8];
        #pragma unroll
        for (int qb = 0; qb < 8; ++qb) {
            const int q = qb * 16 + l15;
            pf[qb] = *(const half8*)(Pb + q * 64 + ((g ^ ((q >> 1) & 3)) << 4));
        }
        #pragma unroll
        for (int qb = 0; qb < 8; ++qb) {
            float sc = scb[qb * 16 + l15];
            if (__any(sc != 1.0f)) {
                #pragma unroll
                for (int nbi = 0; nbi < 5; ++nbi) O[nbi][qb] *= sc;
            }
        }
        __builtin_amdgcn_s_setprio(1);
        #pragma unroll
        for (int nbi = 0; nbi < 5; ++nbi) {
            half8 af = __builtin_bit_cast(half8, afr[nbi]);
            #pragma unroll
            for (int qb = 0; qb < 8; ++qb)
                O[nbi][qb] = __builtin_amdgcn_mfma_f32_16x16x32_f16(af, pf[qb], O[nbi][qb], 0, 0, 0);
        }
        __builtin_amdgcn_s_setprio(0);
        // next iteration's (a)-barrier orders P/buf reuse
    }

    asm volatile("s_waitcnt vmcnt(0)" ::: "memory");

    // ---- store partials ----
    #pragma unroll
    for (int nbi = 0; nbi < 5; ++nbi) {
        const int nb = nbi * 4 + wv;
        #pragma unroll
        for (int qb = 0; qb < 8; ++qb) {
            float* op = opart + ((size_t)bs * N_ROWS + qblk + qb * 16 + l15) * DP + nb * 16 + g * 4;
            *(floatx4*)op = O[nbi][qb];
        }
    }
    if (l15 == 0) {
        #pragma unroll
        for (int c = 0; c < 2; ++c)
            #pragma unroll
            for (int r = 0; r < 4; ++r) {
                mpart[(size_t)bs * N_ROWS + qw + c * 16 + g * 4 + r] = mx[c][r];
                lpart[(size_t)bs * N_ROWS + qw + c * 16 + g * 4 + r] = ls[c][r];
            }
    }
}

// ---------------- kernel 4: combine slice partials + default column (verified) ----------------
__global__ __launch_bounds__(256) void k_combine(const float* __restrict__ words,
                                                 const float* __restrict__ sdef,
                                                 const float* __restrict__ opart,
                                                 const float* __restrict__ mpart,
                                                 const float* __restrict__ lpart,
                                                 float* __restrict__ out) {
    const int gid = blockIdx.x * 256 + threadIdx.x;
    const int q = gid / DP;
    const int d = gid % DP;
    if (q >= N_ROWS) return;
    float sd = sdef[q];
    float M = sd;
    #pragma unroll
    for (int j = 0; j < VSLICE; ++j) M = fmaxf(M, mpart[(size_t)j * N_ROWS + q]);
    float ed = __expf(sd - M);
    float denom = ed;
    float acc = (d < DIM) ? ed * words[(size_t)q * DIM + d] : 0.f;
    #pragma unroll
    for (int j = 0; j < VSLICE; ++j) {
        float e = __expf(mpart[(size_t)j * N_ROWS + q] - M);
        denom += lpart[(size_t)j * N_ROWS + q] * e;
        acc += e * opart[((size_t)j * N_ROWS + q) * DP + d];
    }
    if (d < DIM) out[(size_t)q * DIM + d] = acc / denom;
}

// ---------------- launcher ----------------
extern "C" void kernel_launch(void* const* d_in, const int* in_sizes, int n_in,
                              void* d_out, int out_size, void* d_ws, size_t ws_size,
                              hipStream_t stream) {
    const float* words = (const float*)d_in[0];
    const float* vocab = (const float*)d_in[1];
    const float* de    = (const float*)d_in[2];
    const float* W     = (const float*)d_in[3];

    char* ws = (char*)d_ws;
    unsigned short* proj_hi = (unsigned short*)(ws + OFF_PROJ_HI);
    unsigned short* proj_lo = (unsigned short*)(ws + OFF_PROJ_LO);
    float*          sdef    = (float*)(ws + OFF_SDEF);
    unsigned short* vh      = (unsigned short*)(ws + OFF_VH);
    unsigned short* vt      = (unsigned short*)(ws + OFF_VT);
    float*          opart   = (float*)(ws + OFF_OP);
    float*          mpart   = (float*)(ws + OFF_MP);
    float*          lpart   = (float*)(ws + OFF_LP);

    hipLaunchKernelGGL(k_proj,    dim3(N_ROWS / 16), dim3(256), 0, stream,
                       words, W, de, proj_hi, proj_lo, sdef);
    hipLaunchKernelGGL(k_vocab,   dim3(784 * 5), dim3(256), 0, stream,
                       vocab, vh, vt);
    hipLaunchKernelGGL(k_attn,    dim3(RB * VSLICE), dim3(256), 0, stream,
                       proj_hi, proj_lo, vh, vt, opart, mpart, lpart);
    hipLaunchKernelGGL(k_combine, dim3((N_ROWS * DP) / 256), dim3(256), 0, stream,
                       words, sdef, opart, mpart, lpart, (float*)d_out);
}